// Round 3
// baseline (337.026 us; speedup 1.0000x reference)
//
#include <hip/hip_runtime.h>
#include <cstdint>
#include <cstddef>

typedef unsigned short u16;
typedef unsigned int u32;
typedef __attribute__((ext_vector_type(8))) short short8;
typedef __attribute__((ext_vector_type(4))) float f32x4;

__device__ __forceinline__ float bf2f(u16 v) { return __uint_as_float((u32)v << 16); }
__device__ __forceinline__ u16 f2bf(float f) {
    u32 u = __float_as_uint(f);
    u = (u + 0x7fffu + ((u >> 16) & 1u)) >> 16;   // RNE, finite values only
    return (u16)u;
}

// ------------------------------------------------------------------
// Kernel 0: sniff input dtype. x ~ N(0,1). If bf16, every u16 is a plausible
// normal (exp field in ~[96,135]). If fp32, even-index u16s are low mantissa
// words (uniform bits): only ~16% land in that exp range. flag=1 -> fp32.
// ------------------------------------------------------------------
__global__ void detect_kernel(const u16* __restrict__ x, int* __restrict__ flag) {
    int cnt = 0;
    for (int i = threadIdx.x; i < 256; i += 64) {
        const int e = (x[2 * i] >> 7) & 0xFF;
        cnt += (e >= 96 && e <= 135) ? 1 : 0;
    }
    #pragma unroll
    for (int o = 32; o; o >>= 1) cnt += __shfl_down(cnt, o, 64);
    if (threadIdx.x == 0) *flag = (cnt < 128) ? 1 : 0;
}

// ------------------------------------------------------------------
// Kernel 1: W [384,768] -> bf16 copy (from fp32 or bf16 source).
// ------------------------------------------------------------------
__global__ void wconv_kernel(const void* __restrict__ w, u16* __restrict__ wbf,
                             const int* __restrict__ flag) {
    const int i = blockIdx.x * 256 + threadIdx.x;
    if (i >= 384 * 768) return;
    if (*flag) wbf[i] = f2bf(((const float*)w)[i]);
    else       wbf[i] = ((const u16*)w)[i];
}

// ------------------------------------------------------------------
// Kernel 2: x_j stencil + c8-interleave x and x_j (bf16) into xc.
// xc layout: [b][group 0..95][hw][8ch]; groups 0..47 = x, 48..95 = x_j.
// grid (48,16), block 256; one block = 8 channel planes of one batch.
// ------------------------------------------------------------------
__global__ __launch_bounds__(256) void xj_kernel(const void* __restrict__ xin,
                                                 u16* __restrict__ xc,
                                                 const int* __restrict__ flag) {
    const int cg = blockIdx.x, b = blockIdx.y;
    const int fp = *flag;
    __shared__ u16 pl[8][3136];

    const size_t plane0 = ((size_t)b * 384 + (size_t)cg * 8) * 3136;
    if (fp) {
        const float* xb = (const float*)xin + plane0;
        #pragma unroll
        for (int c = 0; c < 8; ++c) {
            const float4* src = (const float4*)(xb + (size_t)c * 3136);
            for (int i = threadIdx.x; i < 784; i += 256) {
                const float4 v = src[i];
                const u32 lo = (u32)f2bf(v.x) | ((u32)f2bf(v.y) << 16);
                const u32 hi = (u32)f2bf(v.z) | ((u32)f2bf(v.w) << 16);
                *(uint2*)&pl[c][i * 4] = make_uint2(lo, hi);
            }
        }
    } else {
        const u16* xb = (const u16*)xin + plane0;
        #pragma unroll
        for (int c = 0; c < 8; ++c) {
            const uint4* src = (const uint4*)(xb + (size_t)c * 3136);
            uint4* dst = (uint4*)(&pl[c][0]);
            for (int i = threadIdx.x; i < 392; i += 256) dst[i] = src[i];
        }
    }
    __syncthreads();

    for (int p = threadIdx.x; p < 3136; p += 256) {
        const int h = p / 56;
        const int w = p - h * 56;
        int off[20];
        const int S[5] = {1, 3, 7, 15, 31};
        #pragma unroll
        for (int si = 0; si < 5; ++si) {
            const int s = S[si];
            int hp = h + s; if (hp >= 56) hp -= 56;
            int hm = h - s; if (hm < 0)   hm += 56;
            int wp = w + s; if (wp >= 56) wp -= 56;
            int wm = w - s; if (wm < 0)   wm += 56;
            off[si * 4 + 0] = hp * 56 + w;
            off[si * 4 + 1] = hm * 56 + w;
            off[si * 4 + 2] = h * 56 + wp;
            off[si * 4 + 3] = h * 56 + wm;
        }
        u32 xq[4], jq[4];
        #pragma unroll
        for (int c = 0; c < 8; ++c) {
            const u16 raw = pl[c][p];
            const float xv = bf2f(raw);
            float mn = xv;                       // include self -> max(0, ...)
            #pragma unroll
            for (int k = 0; k < 20; ++k) mn = fminf(mn, bf2f(pl[c][off[k]]));
            const u16 jv = f2bf(xv - mn);
            if (c & 1) { xq[c >> 1] |= (u32)raw << 16; jq[c >> 1] |= (u32)jv << 16; }
            else       { xq[c >> 1]  = raw;            jq[c >> 1]  = jv; }
        }
        u16* px = xc + ((((size_t)b * 96) + cg) * 3136 + p) * 8;
        u16* pj = xc + ((((size_t)b * 96) + 48 + cg) * 3136 + p) * 8;
        *(uint4*)px = make_uint4(xq[0], xq[1], xq[2], xq[3]);
        *(uint4*)pj = make_uint4(jq[0], jq[1], jq[2], jq[3]);
    }
}

// ------------------------------------------------------------------
// Kernel 3: Y = Wbf[384,768] @ Xc[768,50176] + BN + exact GELU.
// 128x128 tile, 4 waves 2x2, each 64x64 via 4x4 mfma 16x16x32 bf16.
// Register-mediated staging. grid (392,3), block 256.
// ------------------------------------------------------------------
__global__ __launch_bounds__(256) void gemm_kernel(
        const u16* __restrict__ xc, const u16* __restrict__ Wt,
        const void* __restrict__ cb, const void* __restrict__ bsc,
        const void* __restrict__ bbi, const void* __restrict__ bme,
        const void* __restrict__ bva, void* __restrict__ outp,
        const int* __restrict__ flag) {
    const int ntile = blockIdx.x;   // 0..391
    const int mtile = blockIdx.y;   // 0..2
    const int fp = *flag;
    __shared__ u16 As[128 * 32];
    __shared__ u16 Bs[128 * 32];
    __shared__ float2 PB[128];

    const int tid = threadIdx.x;
    if (tid < 128) {
        const int o = mtile * 128 + tid;
        float vsc, vva, vcb, vme, vbi;
        if (fp) {
            vsc = ((const float*)bsc)[o]; vva = ((const float*)bva)[o];
            vcb = ((const float*)cb)[o];  vme = ((const float*)bme)[o];
            vbi = ((const float*)bbi)[o];
        } else {
            vsc = bf2f(((const u16*)bsc)[o]); vva = bf2f(((const u16*)bva)[o]);
            vcb = bf2f(((const u16*)cb)[o]);  vme = bf2f(((const u16*)bme)[o]);
            vbi = bf2f(((const u16*)bbi)[o]);
        }
        const float seff = vsc * rsqrtf(vva + 1e-5f);
        PB[tid] = make_float2(seff, (vcb - vme) * seff + vbi);
    }

    const int lane = tid & 63, wv = tid >> 6;
    const int m0w = (wv >> 1) * 64, n0w = (wv & 1) * 64;
    const int quad = lane >> 4, l16 = lane & 15;

    const u16* agp[2]; u16* aldp[2];
    const u16* bgp[2]; u16* bldp[2];
    #pragma unroll
    for (int p = 0; p < 2; ++p) {
        const int idx = p * 256 + tid;          // 0..511
        agp[p]  = Wt + (size_t)(mtile * 128 + (idx >> 2)) * 768 + (idx & 3) * 8;
        aldp[p] = As + idx * 8;
        const int kg = idx >> 7, n = idx & 127;
        const int g  = ntile * 128 + n;
        const int bb = g / 3136;
        const int hw = g - bb * 3136;
        bgp[p]  = xc + (((size_t)bb * 96 + kg) * 3136 + hw) * 8;
        bldp[p] = Bs + idx * 8;
    }
    const u16* aptr[4]; const u16* bptr[4];
    #pragma unroll
    for (int i = 0; i < 4; ++i) {
        aptr[i] = As + (m0w + i * 16 + l16) * 32 + quad * 8;
        bptr[i] = Bs + (quad * 128 + (n0w + i * 16 + l16)) * 8;
    }

    f32x4 acc[4][4];
    #pragma unroll
    for (int im = 0; im < 4; ++im)
        #pragma unroll
        for (int in = 0; in < 4; ++in)
            acc[im][in] = {0.f, 0.f, 0.f, 0.f};

    for (int kk = 0; kk < 24; ++kk) {
        uint4 ra[2], rb[2];
        #pragma unroll
        for (int p = 0; p < 2; ++p) ra[p] = *(const uint4*)(agp[p] + kk * 32);
        #pragma unroll
        for (int p = 0; p < 2; ++p) rb[p] = *(const uint4*)(bgp[p] + (size_t)kk * 100352);
        __syncthreads();
        #pragma unroll
        for (int p = 0; p < 2; ++p) *(uint4*)aldp[p] = ra[p];
        #pragma unroll
        for (int p = 0; p < 2; ++p) *(uint4*)bldp[p] = rb[p];
        __syncthreads();

        short8 af[4], bfv[4];
        #pragma unroll
        for (int i = 0; i < 4; ++i) af[i]  = *(const short8*)aptr[i];
        #pragma unroll
        for (int i = 0; i < 4; ++i) bfv[i] = *(const short8*)bptr[i];
        #pragma unroll
        for (int im = 0; im < 4; ++im)
            #pragma unroll
            for (int in = 0; in < 4; ++in)
                acc[im][in] = __builtin_amdgcn_mfma_f32_16x16x32_bf16(
                                  af[im], bfv[in], acc[im][in], 0, 0, 0);
    }

    size_t nbase[4];
    #pragma unroll
    for (int in = 0; in < 4; ++in) {
        const int g  = ntile * 128 + n0w + in * 16 + l16;
        const int bb = g / 3136;
        const int hw = g - bb * 3136;
        nbase[in] = (size_t)bb * 384 * 3136 + hw;
    }
    #pragma unroll
    for (int im = 0; im < 4; ++im) {
        #pragma unroll
        for (int r = 0; r < 4; ++r) {
            const int ml = m0w + im * 16 + quad * 4 + r;   // D row = quad*4 + reg
            const float2 sb = PB[ml];
            const int o = mtile * 128 + ml;
            #pragma unroll
            for (int in = 0; in < 4; ++in) {
                float v = acc[im][in][r] * sb.x + sb.y;
                v = 0.5f * v * (1.0f + erff(v * 0.70710678118654752f));
                const size_t oi = nbase[in] + (size_t)o * 3136;
                if (fp) ((float*)outp)[oi] = v;
                else    ((u16*)outp)[oi]   = f2bf(v);
            }
        }
    }
}

extern "C" void kernel_launch(void* const* d_in, const int* in_sizes, int n_in,
                              void* d_out, int out_size, void* d_ws, size_t ws_size,
                              hipStream_t stream) {
    const void* x   = d_in[0];
    const void* w   = d_in[1];
    const void* cbp = d_in[2];
    const void* bsc = d_in[3];
    const void* bbi = d_in[4];
    const void* bme = d_in[5];
    const void* bva = d_in[6];

    int* flag = (int*)d_ws;
    u16* xc   = (u16*)((char*)d_ws + 64);            // 77,070,336 B
    u16* wbf  = xc + (size_t)16 * 96 * 3136 * 8;     // 589,824 B
    // total ws use: ~77.7 MB

    detect_kernel<<<1, 64, 0, stream>>>((const u16*)x, flag);
    wconv_kernel<<<1152, 256, 0, stream>>>(w, wbf, flag);
    xj_kernel<<<dim3(48, 16), 256, 0, stream>>>(x, xc, flag);
    gemm_kernel<<<dim3(392, 3), 256, 0, stream>>>(xc, wbf, cbp, bsc, bbi, bme, bva,
                                                  d_out, flag);
}

// Round 4
// 330.659 us; speedup vs baseline: 1.0193x; 1.0193x over previous
//
#include <hip/hip_runtime.h>
#include <cstdint>
#include <cstddef>

typedef unsigned short u16;
typedef unsigned int u32;
typedef __attribute__((ext_vector_type(8))) short short8;
typedef __attribute__((ext_vector_type(4))) float f32x4;

__device__ __forceinline__ float bf2f(u16 v) { return __uint_as_float((u32)v << 16); }
__device__ __forceinline__ u16 f2bf(float f) {
    u32 u = __float_as_uint(f);
    u = (u + 0x7fffu + ((u >> 16) & 1u)) >> 16;   // RNE, finite values only
    return (u16)u;
}

// async global->LDS, 16 B/lane; LDS dest must be wave-uniform base + lane*16
#define GLD16(g, l) __builtin_amdgcn_global_load_lds( \
    (const __attribute__((address_space(1))) void*)(g), \
    (__attribute__((address_space(3))) void*)(l), 16, 0, 0)

// ------------------------------------------------------------------
// Kernel 0: dtype sniffer (flag=1 -> fp32 inputs). See round-3 notes.
// ------------------------------------------------------------------
__global__ void detect_kernel(const u16* __restrict__ x, int* __restrict__ flag) {
    int cnt = 0;
    for (int i = threadIdx.x; i < 256; i += 64) {
        const int e = (x[2 * i] >> 7) & 0xFF;
        cnt += (e >= 96 && e <= 135) ? 1 : 0;
    }
    #pragma unroll
    for (int o = 32; o; o >>= 1) cnt += __shfl_down(cnt, o, 64);
    if (threadIdx.x == 0) *flag = (cnt < 128) ? 1 : 0;
}

// ------------------------------------------------------------------
// Kernel 1: W [384,768] -> bf16.
// ------------------------------------------------------------------
__global__ void wconv_kernel(const void* __restrict__ w, u16* __restrict__ wbf,
                             const int* __restrict__ flag) {
    const int i = blockIdx.x * 256 + threadIdx.x;
    if (i >= 384 * 768) return;
    if (*flag) wbf[i] = f2bf(((const float*)w)[i]);
    else       wbf[i] = ((const u16*)w)[i];
}

// ------------------------------------------------------------------
// Kernel 2: x_j stencil, pixel-major LDS [3136][8ch] bf16 so each neighbor
// is one ds_read_b128 (8 channels). xc layout: [b][group 0..95][hw][8c];
// groups 0..47 = x copy, 48..95 = x_j. grid (48,16), block 256.
// ------------------------------------------------------------------
__global__ __launch_bounds__(256) void xj_kernel(const void* __restrict__ xin,
                                                 u16* __restrict__ xc,
                                                 const int* __restrict__ flag) {
    const int cg = blockIdx.x, b = blockIdx.y;
    const int fp = *flag;
    __shared__ __align__(16) u16 pl[3136][8];   // 50,176 B
    const size_t plane0 = ((size_t)b * 384 + (size_t)cg * 8) * 3136;

    if (fp) {
        const float* xb = (const float*)xin + plane0;
        for (int g = threadIdx.x; g < 784; g += 256) {
            const int p = g * 4;
            float vv[8][4];
            #pragma unroll
            for (int c = 0; c < 8; ++c) {
                const float4 t = *(const float4*)(xb + (size_t)c * 3136 + p);
                vv[c][0] = t.x; vv[c][1] = t.y; vv[c][2] = t.z; vv[c][3] = t.w;
            }
            #pragma unroll
            for (int i = 0; i < 4; ++i) {
                u32 q[4];
                #pragma unroll
                for (int cc = 0; cc < 4; ++cc)
                    q[cc] = (u32)f2bf(vv[cc * 2][i]) | ((u32)f2bf(vv[cc * 2 + 1][i]) << 16);
                *(uint4*)&pl[p + i][0] = make_uint4(q[0], q[1], q[2], q[3]);
            }
        }
    } else {
        const u16* xb = (const u16*)xin + plane0;
        for (int g = threadIdx.x; g < 784; g += 256) {
            const int p = g * 4;
            u32 rc[8][2];
            #pragma unroll
            for (int c = 0; c < 8; ++c) {
                const uint2 t = *(const uint2*)(xb + (size_t)c * 3136 + p);
                rc[c][0] = t.x; rc[c][1] = t.y;
            }
            #pragma unroll
            for (int i = 0; i < 4; ++i) {
                const int d = i >> 1, sh = (i & 1) * 16;
                u32 q[4];
                #pragma unroll
                for (int cc = 0; cc < 4; ++cc) {
                    const u32 lo = (rc[cc * 2][d] >> sh) & 0xFFFFu;
                    const u32 hi = (rc[cc * 2 + 1][d] >> sh) & 0xFFFFu;
                    q[cc] = lo | (hi << 16);
                }
                *(uint4*)&pl[p + i][0] = make_uint4(q[0], q[1], q[2], q[3]);
            }
        }
    }
    __syncthreads();

    for (int p = threadIdx.x; p < 3136; p += 256) {
        const int h = p / 56, w = p - h * 56;
        int off[20];
        const int S[5] = {1, 3, 7, 15, 31};
        #pragma unroll
        for (int si = 0; si < 5; ++si) {
            const int s = S[si];
            int hp = h + s; if (hp >= 56) hp -= 56;
            int hm = h - s; if (hm < 0)   hm += 56;
            int wp = w + s; if (wp >= 56) wp -= 56;
            int wm = w - s; if (wm < 0)   wm += 56;
            off[si * 4 + 0] = hp * 56 + w;
            off[si * 4 + 1] = hm * 56 + w;
            off[si * 4 + 2] = h * 56 + wp;
            off[si * 4 + 3] = h * 56 + wm;
        }
        const uint4 self = *(const uint4*)&pl[p][0];
        const u32 sw[4] = {self.x, self.y, self.z, self.w};
        float xv[8], mn[8];
        #pragma unroll
        for (int c2 = 0; c2 < 4; ++c2) {
            xv[c2 * 2]     = __uint_as_float(sw[c2] << 16);
            xv[c2 * 2 + 1] = __uint_as_float(sw[c2] & 0xFFFF0000u);
            mn[c2 * 2] = xv[c2 * 2]; mn[c2 * 2 + 1] = xv[c2 * 2 + 1];
        }
        #pragma unroll
        for (int k = 0; k < 20; ++k) {
            const uint4 nb = *(const uint4*)&pl[off[k]][0];
            const u32 nw[4] = {nb.x, nb.y, nb.z, nb.w};
            #pragma unroll
            for (int c2 = 0; c2 < 4; ++c2) {
                mn[c2 * 2]     = fminf(mn[c2 * 2],     __uint_as_float(nw[c2] << 16));
                mn[c2 * 2 + 1] = fminf(mn[c2 * 2 + 1], __uint_as_float(nw[c2] & 0xFFFF0000u));
            }
        }
        u32 jq[4];
        #pragma unroll
        for (int c2 = 0; c2 < 4; ++c2)
            jq[c2] = (u32)f2bf(xv[c2 * 2] - mn[c2 * 2]) |
                     ((u32)f2bf(xv[c2 * 2 + 1] - mn[c2 * 2 + 1]) << 16);
        u16* px = xc + ((((size_t)b * 96) + cg) * 3136 + p) * 8;
        u16* pj = xc + ((((size_t)b * 96) + 48 + cg) * 3136 + p) * 8;
        *(uint4*)px = self;
        *(uint4*)pj = make_uint4(jq[0], jq[1], jq[2], jq[3]);
    }
}

// ------------------------------------------------------------------
// Kernel 3: Y = Wbf[384,768] @ Xc[768,50176] + BN + exact GELU.
// Tile M=384 (full) x N=64 -> xc fetched exactly once. 4 waves, each 96x64
// (6x4 frags of mfma 16x16x32 bf16). GLD16 async staging, m97 2-barrier
// K-loop (24 iters of BK=32). Epilogue: per-wave LDS transpose -> 256 B
// contiguous row stores. grid (784), block 256.
// ------------------------------------------------------------------
__global__ __launch_bounds__(256) void gemm_kernel(
        const u16* __restrict__ xc, const u16* __restrict__ Wt,
        const void* __restrict__ cb, const void* __restrict__ bsc,
        const void* __restrict__ bbi, const void* __restrict__ bme,
        const void* __restrict__ bva, void* __restrict__ outp,
        const int* __restrict__ flag) {
    const int ntile = blockIdx.x;             // 0..783
    const int fp = *flag;
    __shared__ __align__(16) u16 As[384 * 32];   // 24,576 B (reused as epilogue T)
    __shared__ __align__(16) u16 Bs[32 * 64];    //  4,096 B
    __shared__ float2 PB[384];

    const int tid = threadIdx.x;
    for (int i = tid; i < 384; i += 256) {
        float vsc, vva, vcb, vme, vbi;
        if (fp) {
            vsc = ((const float*)bsc)[i]; vva = ((const float*)bva)[i];
            vcb = ((const float*)cb)[i];  vme = ((const float*)bme)[i];
            vbi = ((const float*)bbi)[i];
        } else {
            vsc = bf2f(((const u16*)bsc)[i]); vva = bf2f(((const u16*)bva)[i]);
            vcb = bf2f(((const u16*)cb)[i]);  vme = bf2f(((const u16*)bme)[i]);
            vbi = bf2f(((const u16*)bbi)[i]);
        }
        const float seff = vsc * rsqrtf(vva + 1e-5f);
        PB[i] = make_float2(seff, (vcb - vme) * seff + vbi);
    }

    const int lane = tid & 63, wv = tid >> 6;
    const int quad = lane >> 4, l16 = lane & 15;
    const int bb  = ntile / 49;
    const int hw0 = (ntile - bb * 49) * 64;

    // A staging: 384 rows x 4 chunks = 1536 16B-chunks, 6 per thread
    const u16* agp[6]; u16* aldp[6];
    #pragma unroll
    for (int i = 0; i < 6; ++i) {
        const int idx = i * 256 + tid;
        agp[i]  = Wt + (size_t)(idx >> 2) * 768 + (idx & 3) * 8;
        aldp[i] = As + idx * 8;
    }
    // B staging: 4 kg-groups x 64 cols = 256 chunks, 1 per thread
    const int kg0 = tid >> 6, bn = tid & 63;
    const u16* bgp = xc + (((size_t)bb * 96 + kg0) * 3136 + hw0 + bn) * 8;
    u16* bldp = Bs + tid * 8;

    const u16* aptr[6]; const u16* bptr[4];
    #pragma unroll
    for (int i = 0; i < 6; ++i) aptr[i] = As + (wv * 96 + i * 16 + l16) * 32 + quad * 8;
    #pragma unroll
    for (int i = 0; i < 4; ++i) bptr[i] = Bs + (quad * 64 + i * 16 + l16) * 8;

    f32x4 acc[6][4];
    #pragma unroll
    for (int im = 0; im < 6; ++im)
        #pragma unroll
        for (int in = 0; in < 4; ++in)
            acc[im][in] = {0.f, 0.f, 0.f, 0.f};

    for (int kk = 0; kk < 24; ++kk) {
        #pragma unroll
        for (int i = 0; i < 6; ++i) GLD16(agp[i] + kk * 32, aldp[i]);
        GLD16(bgp + (size_t)kk * 4 * 3136 * 8, bldp);
        __syncthreads();   // vmcnt drain: tile resident

        short8 af[6], bfv[4];
        #pragma unroll
        for (int i = 0; i < 6; ++i) af[i]  = *(const short8*)aptr[i];
        #pragma unroll
        for (int i = 0; i < 4; ++i) bfv[i] = *(const short8*)bptr[i];
        #pragma unroll
        for (int im = 0; im < 6; ++im)
            #pragma unroll
            for (int in = 0; in < 4; ++in)
                acc[im][in] = __builtin_amdgcn_mfma_f32_16x16x32_bf16(
                                  af[im], bfv[in], acc[im][in], 0, 0, 0);
        __syncthreads();   // protect LDS before next iter's GLD16
    }

    // --- epilogue: BN + exact GELU, per-wave LDS transpose, coalesced stores ---
    float* T = (float*)As + wv * (16 * 68);   // 4352 B per wave, private region
    const size_t obase = (size_t)bb * 384 * 3136 + hw0;
    #pragma unroll
    for (int im = 0; im < 6; ++im) {
        #pragma unroll
        for (int r = 0; r < 4; ++r) {
            const int ml = wv * 96 + im * 16 + quad * 4 + r;   // D row = quad*4 + reg
            const float2 sb = PB[ml];
            #pragma unroll
            for (int in = 0; in < 4; ++in) {
                float v = acc[im][in][r] * sb.x + sb.y;
                v = 0.5f * v * (1.0f + erff(v * 0.70710678118654752f));
                T[(quad * 4 + r) * 68 + in * 16 + l16] = v;
            }
        }
        asm volatile("s_waitcnt lgkmcnt(0)" ::: "memory");   // writes visible in-wave
        #pragma unroll
        for (int it = 0; it < 4; ++it) {
            const int flat = it * 256 + lane * 4;   // 0..1023
            const int row = flat >> 6, col = flat & 63;
            const float4 vv = *(const float4*)&T[row * 68 + col];
            const size_t oi = obase + (size_t)(wv * 96 + im * 16 + row) * 3136 + col;
            if (fp) {
                *(float4*)((float*)outp + oi) = vv;
            } else {
                const u32 a = (u32)f2bf(vv.x) | ((u32)f2bf(vv.y) << 16);
                const u32 b2 = (u32)f2bf(vv.z) | ((u32)f2bf(vv.w) << 16);
                *(uint2*)((u16*)outp + oi) = make_uint2(a, b2);
            }
        }
        asm volatile("s_waitcnt lgkmcnt(0)" ::: "memory");   // reads done before next im
    }
}

extern "C" void kernel_launch(void* const* d_in, const int* in_sizes, int n_in,
                              void* d_out, int out_size, void* d_ws, size_t ws_size,
                              hipStream_t stream) {
    const void* x   = d_in[0];
    const void* w   = d_in[1];
    const void* cbp = d_in[2];
    const void* bsc = d_in[3];
    const void* bbi = d_in[4];
    const void* bme = d_in[5];
    const void* bva = d_in[6];

    int* flag = (int*)d_ws;
    u16* xc   = (u16*)((char*)d_ws + 64);            // 77,070,336 B
    u16* wbf  = xc + (size_t)16 * 96 * 3136 * 8;     // 589,824 B

    detect_kernel<<<1, 64, 0, stream>>>((const u16*)x, flag);
    wconv_kernel<<<1152, 256, 0, stream>>>(w, wbf, flag);
    xj_kernel<<<dim3(48, 16), 256, 0, stream>>>(x, xc, flag);
    gemm_kernel<<<784, 256, 0, stream>>>(xc, wbf, cbp, bsc, bbi, bme, bva, d_out, flag);
}

// Round 5
// 264.279 us; speedup vs baseline: 1.2753x; 1.2512x over previous
//
#include <hip/hip_runtime.h>
#include <cstdint>
#include <cstddef>

typedef unsigned short u16;
typedef unsigned int u32;
typedef __attribute__((ext_vector_type(8))) short short8;
typedef __attribute__((ext_vector_type(4))) float f32x4;

__device__ __forceinline__ float bf2f(u16 v) { return __uint_as_float((u32)v << 16); }
__device__ __forceinline__ u16 f2bf(float f) {
    u32 u = __float_as_uint(f);
    u = (u + 0x7fffu + ((u >> 16) & 1u)) >> 16;   // RNE, finite values only
    return (u16)u;
}

// async global->LDS, 16 B/lane; LDS dest must be wave-uniform base + lane*16
#define GLD16(g, l) __builtin_amdgcn_global_load_lds( \
    (const __attribute__((address_space(1))) void*)(g), \
    (__attribute__((address_space(3))) void*)(l), 16, 0, 0)

// ------------------------------------------------------------------
// Kernel 0: dtype sniffer (flag=1 -> fp32 inputs).
// ------------------------------------------------------------------
__global__ void detect_kernel(const u16* __restrict__ x, int* __restrict__ flag) {
    int cnt = 0;
    for (int i = threadIdx.x; i < 256; i += 64) {
        const int e = (x[2 * i] >> 7) & 0xFF;
        cnt += (e >= 96 && e <= 135) ? 1 : 0;
    }
    #pragma unroll
    for (int o = 32; o; o >>= 1) cnt += __shfl_down(cnt, o, 64);
    if (threadIdx.x == 0) *flag = (cnt < 128) ? 1 : 0;
}

// ------------------------------------------------------------------
// Kernel 1: W [384,768] -> bf16.
// ------------------------------------------------------------------
__global__ void wconv_kernel(const void* __restrict__ w, u16* __restrict__ wbf,
                             const int* __restrict__ flag) {
    const int i = blockIdx.x * 256 + threadIdx.x;
    if (i >= 384 * 768) return;
    if (*flag) wbf[i] = f2bf(((const float*)w)[i]);
    else       wbf[i] = ((const u16*)w)[i];
}

// ------------------------------------------------------------------
// Kernel 2: x_j stencil, pixel-major LDS [3136][8ch]. (unchanged from r4)
// xc layout: [b][group 0..95][hw][8c]; groups 0..47 = x, 48..95 = x_j.
// ------------------------------------------------------------------
__global__ __launch_bounds__(256) void xj_kernel(const void* __restrict__ xin,
                                                 u16* __restrict__ xc,
                                                 const int* __restrict__ flag) {
    const int cg = blockIdx.x, b = blockIdx.y;
    const int fp = *flag;
    __shared__ __align__(16) u16 pl[3136][8];
    const size_t plane0 = ((size_t)b * 384 + (size_t)cg * 8) * 3136;

    if (fp) {
        const float* xb = (const float*)xin + plane0;
        for (int g = threadIdx.x; g < 784; g += 256) {
            const int p = g * 4;
            float vv[8][4];
            #pragma unroll
            for (int c = 0; c < 8; ++c) {
                const float4 t = *(const float4*)(xb + (size_t)c * 3136 + p);
                vv[c][0] = t.x; vv[c][1] = t.y; vv[c][2] = t.z; vv[c][3] = t.w;
            }
            #pragma unroll
            for (int i = 0; i < 4; ++i) {
                u32 q[4];
                #pragma unroll
                for (int cc = 0; cc < 4; ++cc)
                    q[cc] = (u32)f2bf(vv[cc * 2][i]) | ((u32)f2bf(vv[cc * 2 + 1][i]) << 16);
                *(uint4*)&pl[p + i][0] = make_uint4(q[0], q[1], q[2], q[3]);
            }
        }
    } else {
        const u16* xb = (const u16*)xin + plane0;
        for (int g = threadIdx.x; g < 784; g += 256) {
            const int p = g * 4;
            u32 rc[8][2];
            #pragma unroll
            for (int c = 0; c < 8; ++c) {
                const uint2 t = *(const uint2*)(xb + (size_t)c * 3136 + p);
                rc[c][0] = t.x; rc[c][1] = t.y;
            }
            #pragma unroll
            for (int i = 0; i < 4; ++i) {
                const int d = i >> 1, sh = (i & 1) * 16;
                u32 q[4];
                #pragma unroll
                for (int cc = 0; cc < 4; ++cc) {
                    const u32 lo = (rc[cc * 2][d] >> sh) & 0xFFFFu;
                    const u32 hi = (rc[cc * 2 + 1][d] >> sh) & 0xFFFFu;
                    q[cc] = lo | (hi << 16);
                }
                *(uint4*)&pl[p + i][0] = make_uint4(q[0], q[1], q[2], q[3]);
            }
        }
    }
    __syncthreads();

    for (int p = threadIdx.x; p < 3136; p += 256) {
        const int h = p / 56, w = p - h * 56;
        int off[20];
        const int S[5] = {1, 3, 7, 15, 31};
        #pragma unroll
        for (int si = 0; si < 5; ++si) {
            const int s = S[si];
            int hp = h + s; if (hp >= 56) hp -= 56;
            int hm = h - s; if (hm < 0)   hm += 56;
            int wp = w + s; if (wp >= 56) wp -= 56;
            int wm = w - s; if (wm < 0)   wm += 56;
            off[si * 4 + 0] = hp * 56 + w;
            off[si * 4 + 1] = hm * 56 + w;
            off[si * 4 + 2] = h * 56 + wp;
            off[si * 4 + 3] = h * 56 + wm;
        }
        const uint4 self = *(const uint4*)&pl[p][0];
        const u32 sw[4] = {self.x, self.y, self.z, self.w};
        float xv[8], mn[8];
        #pragma unroll
        for (int c2 = 0; c2 < 4; ++c2) {
            xv[c2 * 2]     = __uint_as_float(sw[c2] << 16);
            xv[c2 * 2 + 1] = __uint_as_float(sw[c2] & 0xFFFF0000u);
            mn[c2 * 2] = xv[c2 * 2]; mn[c2 * 2 + 1] = xv[c2 * 2 + 1];
        }
        #pragma unroll
        for (int k = 0; k < 20; ++k) {
            const uint4 nb = *(const uint4*)&pl[off[k]][0];
            const u32 nw[4] = {nb.x, nb.y, nb.z, nb.w};
            #pragma unroll
            for (int c2 = 0; c2 < 4; ++c2) {
                mn[c2 * 2]     = fminf(mn[c2 * 2],     __uint_as_float(nw[c2] << 16));
                mn[c2 * 2 + 1] = fminf(mn[c2 * 2 + 1], __uint_as_float(nw[c2] & 0xFFFF0000u));
            }
        }
        u32 jq[4];
        #pragma unroll
        for (int c2 = 0; c2 < 4; ++c2)
            jq[c2] = (u32)f2bf(xv[c2 * 2] - mn[c2 * 2]) |
                     ((u32)f2bf(xv[c2 * 2 + 1] - mn[c2 * 2 + 1]) << 16);
        u16* px = xc + ((((size_t)b * 96) + cg) * 3136 + p) * 8;
        u16* pj = xc + ((((size_t)b * 96) + 48 + cg) * 3136 + p) * 8;
        *(uint4*)px = self;
        *(uint4*)pj = make_uint4(jq[0], jq[1], jq[2], jq[3]);
    }
}

// ------------------------------------------------------------------
// Kernel 3: Y = Wbf[384,768] @ Xc[768,50176] + BN + exact GELU.
// Barrier-light design: A-fragments loaded straight from global (W is
// L2-hot, register loads pipeline via vmcnt); B double-buffered in LDS
// in 6 phases of K=128 (1 cheap barrier per phase, staged a phase ahead).
// Tile M=192 x N=64; 4 waves, each 48x64 = 3x4 frags of mfma 16x16x32.
// grid (784, 2), block 256.
// ------------------------------------------------------------------
__global__ __launch_bounds__(256) void gemm_kernel(
        const u16* __restrict__ xc, const u16* __restrict__ Wt,
        const void* __restrict__ cb, const void* __restrict__ bsc,
        const void* __restrict__ bbi, const void* __restrict__ bme,
        const void* __restrict__ bva, void* __restrict__ outp,
        const int* __restrict__ flag) {
    const int ntile = blockIdx.x;             // 0..783
    const int mtile = blockIdx.y;             // 0..1
    const int fp = *flag;
    __shared__ __align__(16) u16 Bs[2][16 * 64 * 8];   // 2 x 16 KB (reused as T)
    __shared__ float2 PB[192];

    const int tid = threadIdx.x;
    if (tid < 192) {
        const int o = mtile * 192 + tid;
        float vsc, vva, vcb, vme, vbi;
        if (fp) {
            vsc = ((const float*)bsc)[o]; vva = ((const float*)bva)[o];
            vcb = ((const float*)cb)[o];  vme = ((const float*)bme)[o];
            vbi = ((const float*)bbi)[o];
        } else {
            vsc = bf2f(((const u16*)bsc)[o]); vva = bf2f(((const u16*)bva)[o]);
            vcb = bf2f(((const u16*)cb)[o]);  vme = bf2f(((const u16*)bme)[o]);
            vbi = bf2f(((const u16*)bbi)[o]);
        }
        const float seff = vsc * rsqrtf(vva + 1e-5f);
        PB[tid] = make_float2(seff, (vcb - vme) * seff + vbi);
    }

    const int lane = tid & 63, wv = tid >> 6;
    const int quad = lane >> 4, l16 = lane & 15;
    const int bb  = ntile / 49;
    const int hw0 = (ntile - bb * 49) * 64;

    // B staging: phase q covers groups q*16..+16; 1024 16B-chunks, 4/thread.
    const u16* bgp[4]; int bofs[4];
    #pragma unroll
    for (int i = 0; i < 4; ++i) {
        const int idx = i * 256 + tid;        // 0..1023
        const int gg = idx >> 6, n = idx & 63;
        bgp[i]  = xc + (((size_t)bb * 96 + gg) * 3136 + hw0 + n) * 8;
        bofs[i] = idx * 8;
    }
    #define STAGE(q) { \
        u16* dst = &Bs[(q) & 1][0]; \
        _Pragma("unroll") \
        for (int i = 0; i < 4; ++i) GLD16(bgp[i] + (size_t)(q) * 16 * 3136 * 8, dst + bofs[i]); }

    // A-fragment global pointers: row = mtile*192 + wv*48 + im*16 + l16
    const u16* arow[3];
    #pragma unroll
    for (int im = 0; im < 3; ++im)
        arow[im] = Wt + (size_t)(mtile * 192 + wv * 48 + im * 16 + l16) * 768 + quad * 8;

    f32x4 acc[3][4];
    #pragma unroll
    for (int im = 0; im < 3; ++im)
        #pragma unroll
        for (int in = 0; in < 4; ++in)
            acc[im][in] = {0.f, 0.f, 0.f, 0.f};

    STAGE(0);
    __syncthreads();                          // only full-latency drain

    for (int q = 0; q < 6; ++q) {
        if (q < 5) STAGE(q + 1);              // into other buffer, drains at end-of-phase barrier
        const u16* bufq = &Bs[q & 1][0];
        #pragma unroll
        for (int s = 0; s < 4; ++s) {
            const int k0 = q * 128 + s * 32;
            short8 af[3], bfv[4];
            #pragma unroll
            for (int im = 0; im < 3; ++im)
                af[im] = *(const short8*)(arow[im] + k0);
            #pragma unroll
            for (int in = 0; in < 4; ++in)
                bfv[in] = *(const short8*)(bufq + ((s * 4 + quad) * 64 + in * 16 + l16) * 8);
            #pragma unroll
            for (int im = 0; im < 3; ++im)
                #pragma unroll
                for (int in = 0; in < 4; ++in)
                    acc[im][in] = __builtin_amdgcn_mfma_f32_16x16x32_bf16(
                                      af[im], bfv[in], acc[im][in], 0, 0, 0);
        }
        __syncthreads();   // next-phase staging landed; buf[q&1] free for q+2
    }

    // --- epilogue: BN + exact GELU, per-wave LDS transpose, coalesced stores ---
    float* T = (float*)&Bs[0][0] + wv * (16 * 68);   // 4352 B/wave, disjoint
    const size_t obase = (size_t)bb * 384 * 3136 + hw0;
    #pragma unroll
    for (int im = 0; im < 3; ++im) {
        #pragma unroll
        for (int r = 0; r < 4; ++r) {
            const int ml = mtile * 192 + wv * 48 + im * 16 + quad * 4 + r;
            const float2 sb = PB[(wv * 48 + im * 16 + quad * 4 + r)];
            #pragma unroll
            for (int in = 0; in < 4; ++in) {
                float v = acc[im][in][r] * sb.x + sb.y;
                v = 0.5f * v * (1.0f + erff(v * 0.70710678118654752f));
                T[(quad * 4 + r) * 68 + in * 16 + l16] = v;
            }
            (void)ml;
        }
        asm volatile("s_waitcnt lgkmcnt(0)" ::: "memory");
        #pragma unroll
        for (int it = 0; it < 4; ++it) {
            const int flat = it * 256 + lane * 4;   // 0..1023
            const int row = flat >> 6, col = flat & 63;
            const float4 vv = *(const float4*)&T[row * 68 + col];
            const size_t oi = obase +
                (size_t)(mtile * 192 + wv * 48 + im * 16 + row) * 3136 + col;
            if (fp) {
                *(float4*)((float*)outp + oi) = vv;
            } else {
                const u32 a = (u32)f2bf(vv.x) | ((u32)f2bf(vv.y) << 16);
                const u32 b2 = (u32)f2bf(vv.z) | ((u32)f2bf(vv.w) << 16);
                *(uint2*)((u16*)outp + oi) = make_uint2(a, b2);
            }
        }
        asm volatile("s_waitcnt lgkmcnt(0)" ::: "memory");
    }
    #undef STAGE
}

extern "C" void kernel_launch(void* const* d_in, const int* in_sizes, int n_in,
                              void* d_out, int out_size, void* d_ws, size_t ws_size,
                              hipStream_t stream) {
    const void* x   = d_in[0];
    const void* w   = d_in[1];
    const void* cbp = d_in[2];
    const void* bsc = d_in[3];
    const void* bbi = d_in[4];
    const void* bme = d_in[5];
    const void* bva = d_in[6];

    int* flag = (int*)d_ws;
    u16* xc   = (u16*)((char*)d_ws + 64);            // 77,070,336 B
    u16* wbf  = xc + (size_t)16 * 96 * 3136 * 8;     // 589,824 B

    detect_kernel<<<1, 64, 0, stream>>>((const u16*)x, flag);
    wconv_kernel<<<1152, 256, 0, stream>>>(w, wbf, flag);
    xj_kernel<<<dim3(48, 16), 256, 0, stream>>>(x, xc, flag);
    gemm_kernel<<<dim3(784, 2), 256, 0, stream>>>(xc, wbf, cbp, bsc, bbi, bme, bva,
                                                  d_out, flag);
}